// Round 10
// baseline (421.510 us; speedup 1.0000x reference)
//
#include <hip/hip_runtime.h>
#include <cstdint>
#include <math.h>

#define BATCH    65536
#define HIS_LEN  5
#define KIND_LEN 10

typedef float v2f __attribute__((ext_vector_type(2)));
__device__ __forceinline__ v2f mk2(float a, float b){ v2f r; r.x=a; r.y=b; return r; }

// ---- ws layout (fp32 element offsets) — unchanged from round 9 ----
#define OFF_WC1 0        // 12288 [64 o][2 half][4 q][24]
#define OFF_AB1 12288    // 64
#define OFF_W2T 12352    // 2048
#define OFF_AB2 14400    // 32
#define OFF_W3  14432    // 32
#define OFF_AB3 14464    // 1
#define OFF_M1  14720    // 26624 [128 o][4 q][52]
#define OFF_MB1 41344    // 128
#define OFF_M2T 41472    // 8192
#define OFF_MB2 49664    // 64
#define OFF_M3T 49728    // 2048
#define OFF_MB3 51776    // 32
#define OFF_M4  51808    // 32
#define OFF_MB4 51840    // 1
#define PREP_N  51586

// LDS floats: STG[0,6144) | PF[6144,8450) | tp bf16 t2 at 8450 (1024 fl)
#define PF    6144
#define LDSF  9474

typedef const float* fp;

__global__ void din_prep(fp aw1, fp ab1, fp aw2, fp ab2, fp aw3, fp ab3,
                         fp m1,  fp mb1, fp m2,  fp mb2, fp m3,  fp mb3,
                         fp m4,  fp mb4, float* __restrict__ ws){
  int i = blockIdx.x*blockDim.x + threadIdx.x;
  int j = i;
  if(j < 12288){
    int o = j/192, t = j%192;
    int h = t/96; int tt = t - 96*h;
    int q = tt/24, d = tt - 24*q;
    float v = 0.f;
    if(d < 22){
      int idx = 8*(d>>1) + 2*q + (d&1);
      v = (h==0) ? (aw1[o*264+idx] + aw1[o*264+88+idx])
                 : (aw1[o*264+176+idx] - aw1[o*264+88+idx]);
    }
    ws[OFF_WC1 + j] = v; return;
  } j -= 12288;
  if(j < 64){ ws[OFF_AB1 + j] = ab1[j]; return; } j -= 64;
  if(j < 2048){ int o=j/32, p=j%32; ws[OFF_W2T + j] = aw2[p*64 + o]; return; } j -= 2048;
  if(j < 32){ ws[OFF_AB2 + j] = ab2[j]; return; } j -= 32;
  if(j < 32){ ws[OFF_W3  + j] = aw3[j]; return; } j -= 32;
  if(j < 1){ ws[OFF_AB3] = ab3[0]; return; } j -= 1;
  if(j < 26624){
    int o = j/208, r = j%208;
    int q = r/52, t = r-52*q;
    int src;
    if(t<8){ int E = (q==0)?0:(8+8*q); src = E + t; }
    else if(t<30){ int d=t-8; int idx = 8*(d>>1)+2*q+(d&1);
                   src = (idx<8) ? (8+idx) : (32+idx); }
    else { int d=t-30; int idx = 8*(d>>1)+2*q+(d&1); src = 120+idx; }
    ws[OFF_M1 + j] = m1[o*208 + src]; return;
  } j -= 26624;
  if(j < 128){ ws[OFF_MB1 + j] = mb1[j]; return; } j -= 128;
  if(j < 8192){ int o=j/64, p=j%64; ws[OFF_M2T + j] = m2[p*128 + o]; return; } j -= 8192;
  if(j < 64){ ws[OFF_MB2 + j] = mb2[j]; return; } j -= 64;
  if(j < 2048){ int o=j/32, p=j%32; ws[OFF_M3T + j] = m3[p*64 + o]; return; } j -= 2048;
  if(j < 32){ ws[OFF_MB3 + j] = mb3[j]; return; } j -= 32;
  if(j < 32){ ws[OFF_M4  + j] = m4[j];  return; } j -= 32;
  if(j < 1){ ws[OFF_MB4] = mb4[0]; return; }
}

__device__ __forceinline__ float bsum4(float v){
  v += __shfl_xor(v, 1);
  v += __shfl_xor(v, 2);
  return v;
}
__device__ __forceinline__ unsigned short f2bf(float f){
  unsigned int u = __float_as_uint(f);
  return (unsigned short)((u + 0x7fffu + ((u>>16)&1u)) >> 16);
}
__device__ __forceinline__ float bf2f(unsigned short s){
  return __uint_as_float(((unsigned int)s) << 16);
}

__device__ __forceinline__ void gather_slice(const float2* __restrict__ itemp,
                                             const float2* __restrict__ kindp,
                                             int item_idx, const int* __restrict__ kidx,
                                             int q, v2f* f){
  float2 v = itemp[item_idx*4 + q];
  f[0] = mk2(v.x, v.y);
  #pragma unroll
  for(int r=0;r<KIND_LEN;r++){
    int ki = kidx[r];
    float2 w = kindp[ki*4 + q];
    bool m = (ki!=0);
    f[1+r] = m ? mk2(w.x, w.y) : mk2(0.f, 0.f);
  }
}

#define PKF(acc, a, b, vv) do{ (acc) = __builtin_elementwise_fma(mk2((a),(b)), (vv), (acc)); }while(0)

// block = 256 threads; 64 samples/block; quad (q=lane&3) K-splits every dot.
// History weights (h=0 WC1, 24 KB) resident in LDS -> barrier-free hot loop.
__global__ void __launch_bounds__(256, 2)
din_main(const int* __restrict__ userid, const int* __restrict__ itemid,
         const int* __restrict__ age,    const int* __restrict__ gen,
         const int* __restrict__ occ,    const int* __restrict__ item_kind,
         const int* __restrict__ his_id, const int* __restrict__ his_kind,
         const float2* __restrict__ user_emb, const float2* __restrict__ item_emb,
         const float2* __restrict__ age_emb,  const float2* __restrict__ gen_emb,
         const float2* __restrict__ occ_emb,  const float2* __restrict__ kind_emb,
         const float* __restrict__ ws, float* __restrict__ out){
  const int tid  = threadIdx.x;
  const int q    = tid & 3;
  const int sl   = (tid & 63) >> 2;
  const int wave = __builtin_amdgcn_readfirstlane(tid >> 6);
  const int b    = blockIdx.x*64 + wave*16 + sl;

  __shared__ __align__(16) float ls[LDSF];
  float4* ls4 = (float4*)ls;
  const float4* ws4 = (const float4*)ws;
  unsigned short* tp = (unsigned short*)(ls + 8450);

  // ---- persistent staging: AB1,W2T,AB2,W3,AB3 | MB2 | MB3,M4,MB4 ----
  for(int j=tid; j<2306; j+=256){
    float v;
    if(j<2177)      v = ws[12288 + j];
    else if(j<2241) v = ws[49664 + (j-2177)];
    else            v = ws[51776 + (j-2241)];
    ls[PF + j] = v;
  }

  // ---- i2 slice ----
  v2f i2v[11];
  gather_slice(item_emb, kind_emb, itemid[b], item_kind + b*KIND_LEN, q, i2v);

  // ---- phase A: t2 -> bf16 LDS (h=1 rows vs i2), 2 chunks x 32 rows ----
  #pragma unroll 1
  for(int c=0;c<2;c++){
    __syncthreads();
    #pragma unroll
    for(int k=0;k<3;k++){
      int j = k*256 + tid;                  // 768 f4 = 32 rows x 24 f4
      int r = j/24, d4 = j - r*24;
      ls4[j] = ws4[(c*32 + r)*48 + 24 + d4];
    }
    __syncthreads();
    #pragma unroll 1
    for(int o=0;o<32;o++){
      const float4* wr = ls4 + o*24 + 6*q;
      v2f aA = mk2(0.f,0.f), aB = mk2(0.f,0.f);
      #pragma unroll
      for(int k=0;k<5;k++){
        float4 w = wr[k];
        PKF(aA, w.x, w.y, i2v[2*k]);
        PKF(aB, w.z, w.w, i2v[2*k+1]);
      }
      { float4 w = wr[5]; PKF(aA, w.x, w.y, i2v[10]); }
      float s = bsum4((aA.x+aB.x)+(aA.y+aB.y));
      if(q==0) tp[(c*32+o)*64 + wave*16 + sl] = f2bf(s);
    }
  }

  // ---- stage FULL h=0 WC1 (64 rows, 1536 f4 = 24 KB) once ----
  __syncthreads();
  #pragma unroll
  for(int k=0;k<6;k++){
    int j = k*256 + tid;
    int r = j/24, d4 = j - r*24;
    ls4[j] = ws4[r*48 + d4];
  }
  __syncthreads();

  v2f poolv[11];
  #pragma unroll
  for(int d=0;d<11;d++) poolv[d]=mk2(0.f,0.f);

  // ---- history: ZERO barriers, ZERO staging ----
  #pragma unroll 1
  for(int s=0;s<HIS_LEN;s++){
    v2f i1v[11];
    gather_slice(item_emb, kind_emb, his_id[b*HIS_LEN+s],
                 his_kind + (b*HIS_LEN+s)*KIND_LEN, q, i1v);

    v2f h2v[4];
    #pragma unroll
    for(int j=0;j<4;j++) h2v[j]=mk2(0.f,0.f);

    #pragma unroll 1
    for(int o=0;o<64;o++){
      const float4* wr = ls4 + o*24 + 6*q;
      v2f aA = mk2(0.f,0.f), aB = mk2(0.f,0.f);
      #pragma unroll
      for(int k=0;k<5;k++){
        float4 w = wr[k];
        PKF(aA, w.x, w.y, i1v[2*k]);
        PKF(aB, w.z, w.w, i1v[2*k+1]);
      }
      { float4 w = wr[5]; PKF(aA, w.x, w.y, i1v[10]); }
      float full = bsum4((aA.x+aB.x)+(aA.y+aB.y));
      float h = full + bf2f(tp[o*64 + wave*16 + sl]) + ls[PF + o];
      h = fmaxf(h, 0.f);
      v2f hh = mk2(h, h);
      float4 wa = ls4[1552 + o*8 + 2*q];    // W2T in PF
      float4 wb = ls4[1553 + o*8 + 2*q];
      PKF(h2v[0], wa.x, wa.y, hh);
      PKF(h2v[1], wa.z, wa.w, hh);
      PKF(h2v[2], wb.x, wb.y, hh);
      PKF(h2v[3], wb.z, wb.w, hh);
    }
    float scp = 0.f;
    #pragma unroll
    for(int jj=0;jj<4;jj++){
      float hx = fmaxf(h2v[jj].x + ls[PF+2112+8*q+2*jj],   0.f);
      float hy = fmaxf(h2v[jj].y + ls[PF+2112+8*q+2*jj+1], 0.f);
      scp += ls[PF+2144+8*q+2*jj]*hx + ls[PF+2144+8*q+2*jj+1]*hy;
    }
    float sc = bsum4(scp) + ls[PF+2176];
    v2f scv = mk2(sc, sc);
    #pragma unroll
    for(int d=0;d<11;d++){
      v2f t = i1v[d]*scv;
      poolv[d] = __builtin_elementwise_fma(t, i1v[d], poolv[d]);
    }
  }

  // ---- MLP extra slice (q selects table) ----
  v2f exv[4];
  {
    const float2* ep = (q==0)? user_emb : (q==1)? age_emb : (q==2)? gen_emb : occ_emb;
    int ei = (q==0)? userid[b] : (q==1)? age[b] : (q==2)? gen[b] : occ[b];
    #pragma unroll
    for(int k=0;k<4;k++){ float2 v = ep[ei*4+k]; exv[k]=mk2(v.x,v.y); }
  }

  v2f h2m[8];
  #pragma unroll
  for(int j=0;j<8;j++) h2m[j] = mk2(ls[PF+2177+16*q+2*j], ls[PF+2177+16*q+2*j+1]);

  // ---- MLP layers 1+2: 8 chunks x 16 rows (1088 f4 + 16 bias) ----
  #pragma unroll 1
  for(int c=0;c<8;c++){
    __syncthreads();
    #pragma unroll
    for(int k=0;k<5;k++){
      int j = k*256 + tid;
      if(j < 832)       ls4[j] = ws4[3680 + c*832 + j];            // M1S
      else if(j < 1088) ls4[j] = ws4[10368 + c*256 + (j-832)];     // M2T
    }
    if(tid < 16) ls[4352 + tid] = ws[OFF_MB1 + c*16 + tid];
    __syncthreads();
    #pragma unroll 1
    for(int i=0;i<16;i++){
      const float4* wr = ls4 + i*52 + 13*q;
      v2f aA = mk2(0.f,0.f), aB = mk2(0.f,0.f);
      { float4 w = wr[0]; PKF(aA, w.x, w.y, exv[0]); PKF(aB, w.z, w.w, exv[1]); }
      { float4 w = wr[1]; PKF(aA, w.x, w.y, exv[2]); PKF(aB, w.z, w.w, exv[3]); }
      #pragma unroll
      for(int k=0;k<5;k++){
        float4 w = wr[2+k];
        PKF(aA, w.x, w.y, i2v[2*k]);
        PKF(aB, w.z, w.w, i2v[2*k+1]);
      }
      { float4 w = wr[7]; PKF(aA, w.x, w.y, i2v[10]); PKF(aB, w.z, w.w, poolv[0]); }
      #pragma unroll
      for(int k=0;k<5;k++){
        float4 w = wr[8+k];
        PKF(aA, w.x, w.y, poolv[2*k+1]);
        PKF(aB, w.z, w.w, poolv[2*k+2]);
      }
      float h = fmaxf(bsum4((aA.x+aB.x)+(aA.y+aB.y)) + ls[4352+i], 0.f);
      v2f hh = mk2(h, h);
      const float4* w2 = ls4 + 832 + i*16 + 4*q;
      #pragma unroll
      for(int k=0;k<4;k++){
        float4 w = w2[k];
        PKF(h2m[2*k],   w.x, w.y, hh);
        PKF(h2m[2*k+1], w.z, w.w, hh);
      }
    }
  }

  // ---- tail: stage M3T with per-q skew, layers 3+4 ----
  __syncthreads();
  #pragma unroll
  for(int k=0;k<2;k++){
    int j = k*256 + tid;
    ls4[(j>>7)*130 + (j&127)] = ws4[12432 + j];
  }
  __syncthreads();

  float h3p[32];
  #pragma unroll
  for(int j=0;j<32;j++) h3p[j]=0.f;
  #pragma unroll
  for(int i=0;i<16;i++){
    float hv = (i&1) ? h2m[i>>1].y : h2m[i>>1].x;
    float v = fmaxf(hv, 0.f);
    const float4* w3 = ls4 + q*130 + i*8;
    #pragma unroll
    for(int j=0;j<8;j++){
      float4 w = w3[j];
      h3p[4*j]+=w.x*v; h3p[4*j+1]+=w.y*v; h3p[4*j+2]+=w.z*v; h3p[4*j+3]+=w.w*v;
    }
  }
  #pragma unroll
  for(int j=0;j<32;j++) h3p[j] += __shfl_xor(h3p[j], 1);
  #pragma unroll
  for(int j=0;j<32;j++) h3p[j] += __shfl_xor(h3p[j], 2);

  float x = ls[PF+2305];
  #pragma unroll
  for(int j=0;j<32;j++) x += ls[PF+2273+j] * fmaxf(h3p[j] + ls[PF+2241+j], 0.f);

  if(q==0) out[b] = 1.0f/(1.0f + __expf(-x));
}

extern "C" void kernel_launch(void* const* d_in, const int* in_sizes, int n_in,
                              void* d_out, int out_size, void* d_ws, size_t ws_size,
                              hipStream_t stream){
  const int* userid    = (const int*)d_in[0];
  const int* itemid    = (const int*)d_in[1];
  const int* age       = (const int*)d_in[2];
  const int* gen       = (const int*)d_in[3];
  const int* occ       = (const int*)d_in[4];
  const int* item_kind = (const int*)d_in[5];
  const int* his_id    = (const int*)d_in[6];
  const int* his_kind  = (const int*)d_in[7];
  const float2* user_emb = (const float2*)d_in[8];
  const float2* item_emb = (const float2*)d_in[9];
  const float2* age_emb  = (const float2*)d_in[10];
  const float2* gen_emb  = (const float2*)d_in[11];
  const float2* occ_emb  = (const float2*)d_in[12];
  const float2* kind_emb = (const float2*)d_in[13];
  float* ws = (float*)d_ws;

  din_prep<<<(PREP_N+255)/256, 256, 0, stream>>>(
      (fp)d_in[14], (fp)d_in[15], (fp)d_in[16], (fp)d_in[17], (fp)d_in[18], (fp)d_in[19],
      (fp)d_in[20], (fp)d_in[21], (fp)d_in[22], (fp)d_in[23], (fp)d_in[24], (fp)d_in[25],
      (fp)d_in[26], (fp)d_in[27], ws);

  din_main<<<BATCH/64, 256, 0, stream>>>(
      userid, itemid, age, gen, occ, item_kind, his_id, his_kind,
      user_emb, item_emb, age_emb, gen_emb, occ_emb, kind_emb,
      ws, (float*)d_out);
}